// Round 4
// baseline (50.738 us; speedup 1.0000x reference)
//
#include <hip/hip_runtime.h>

// MultiHeadAttention — fused per-token head-mixing attention.
// B=32, S=2048 -> 65536 tokens; E=128; HEADS=32; HEAD_DIM=4.
// out[t] = softmax_over_kh( Q(t)K(t)^T * 0.5 ) V(t)  @ Wo^T + bo, with
// Q/K/V = x[t] @ W{q,k,v}^T reshaped (32 heads x 4 dims).
//
// R4 (from 47us R3): phase-diversity restructure.
//  - BT 32->16, THREADS 256->128 (2 waves/block, grid 4096). LDS 17408 B.
//    Residency still 16 waves/CU (VGPR-bound) but as 8 independent blocks at
//    staggered phases -> MFMA/VALU/LDS/HBM overlap across blocks, narrower
//    barriers, finer tail. R3's 4-wave blocks convoyed (Occupancy 18.7%).
//  - Wo packed f16, attended stored f16, phase 3 mfma_f32_16x16x32_f16
//    (fewer pack ops than bf16 f2bf, better mantissa).
//  - NO min-waves launch-bounds clause (R2 lesson: (256,4) -> VGPR=64 ->
//    scratch spills, 3x slower).

#define TOKENS (32 * 2048)
#define E 128
#define NH 32
#define BT 16           // tokens per block
#define THREADS 128     // 2 waves
#define LPITCH 136      // f16 elems per LDS token row (272 B)

typedef __attribute__((ext_vector_type(8))) short short8;
typedef __attribute__((ext_vector_type(4))) float f32x4;
typedef __fp16 h2_t __attribute__((ext_vector_type(2)));
typedef __fp16 h8_t __attribute__((ext_vector_type(8)));

#if __has_builtin(__builtin_amdgcn_exp2f)
#define EXP2F __builtin_amdgcn_exp2f
#else
#define EXP2F exp2f
#endif

#if __has_builtin(__builtin_amdgcn_rcpf)
#define RCPF __builtin_amdgcn_rcpf
#else
#define RCPF(x) (1.0f / (x))
#endif

static __device__ __forceinline__ unsigned short f2bf(float f) {
    // round-to-nearest-even float -> bf16 bits
    unsigned u = __float_as_uint(f);
    unsigned r = (u + 0x7fffu + ((u >> 16) & 1u)) >> 16;
    return (unsigned short)r;
}

static __device__ __forceinline__ unsigned pk16(float a, float b) {
    return __builtin_bit_cast(unsigned, __builtin_amdgcn_cvt_pkrtz(a, b));
}
static __device__ __forceinline__ h2_t u2h(unsigned u) {
    return __builtin_bit_cast(h2_t, u);
}

// a.x*b.x + a.y*b.y + c  (v_dot2_f32_f16 when available)
static __device__ __forceinline__ float fdot2(h2_t a, h2_t b, float c) {
#if __has_builtin(__builtin_amdgcn_fdot2)
    return __builtin_amdgcn_fdot2(a, b, c, false);
#else
    return (float)a.x * (float)b.x + (float)a.y * (float)b.y + c;
#endif
}

// ---------------------------------------------------------------------------
// Prelude: pack Wq,Wk,Wv (bf16) and Wo (f16) from fp32 [out=128][in=128] into
// MFMA B-fragment order: wpk[proj][nt(8)][ks(4)][lane(64)][j(8)]; for lane l
// (c=l&15, g=l>>4): elem j = W[nt*16+c][ks*32 + g*8 + j].  (kappa(g,j)=g*8+j
// used for BOTH A and B fragments — valid since MFMA pairs A(g,j) with B(g,j).)
// ---------------------------------------------------------------------------
__global__ void pack_w(const float* __restrict__ Wq, const float* __restrict__ Wk,
                       const float* __restrict__ Wv, const float* __restrict__ Wo,
                       unsigned short* __restrict__ wpk) {
    int idx = blockIdx.x * blockDim.x + threadIdx.x;   // 4*8*4*64 = 8192
    if (idx >= 4 * 8 * 4 * 64) return;
    int lane = idx & 63;
    int ks   = (idx >> 6) & 3;
    int nt   = (idx >> 8) & 7;
    int proj = idx >> 11;
    const float* W = (proj == 0) ? Wq : (proj == 1) ? Wk : (proj == 2) ? Wv : Wo;
    int c = lane & 15, g = lane >> 4;
    const float* src = W + (size_t)(nt * 16 + c) * E + ks * 32 + g * 8;
    unsigned short* dst = wpk + (size_t)idx * 8;
    if (proj < 3) {
#pragma unroll
        for (int j = 0; j < 8; ++j) dst[j] = f2bf(src[j]);
    } else {
#pragma unroll
        for (int j = 0; j < 8; ++j)
            dst[j] = __builtin_bit_cast(unsigned short, (__fp16)src[j]);
    }
}

// ---------------------------------------------------------------------------
// Main fused kernel: 16 tokens per block, 2 waves.
// ---------------------------------------------------------------------------
__global__ __launch_bounds__(THREADS) void mha_fused(
        const float* __restrict__ x, const unsigned short* __restrict__ wpk,
        const float* __restrict__ bo, float* __restrict__ out) {
    __shared__ __fp16 qs [BT * LPITCH];          // Q rows  [tok][qh*4+d]  f16
    __shared__ __fp16 ksh[BT * LPITCH];          // K rows  [tok][kh*4+d]  f16
    __shared__ __fp16 vth[BT * LPITCH];          // V^T     [tok][d*32+kh] f16
    __shared__ __fp16 at_[BT * LPITCH];          // attended [tok][qh*4+d] f16

    const int tid  = threadIdx.x;
    const int wave = tid >> 6;
    const int lane = tid & 63;
    const int c = lane & 15, g = lane >> 4;
    const int bt0 = blockIdx.x * BT;

    // ---------------- Phase 1: Q,K,V projections (fused N=384) -------------
    {
        // A fragments: X rows in bf16, kappa(g,j)=g*8+j, reused over all nc
        short8 afrag[4];
        const float* xrow = x + (size_t)(bt0 + c) * E;
#pragma unroll
        for (int ks2 = 0; ks2 < 4; ++ks2) {
            const float* p = xrow + ks2 * 32 + g * 8;
            float4 v0 = *(const float4*)(p);
            float4 v1 = *(const float4*)(p + 4);
            short8 a;
            a[0] = f2bf(v0.x); a[1] = f2bf(v0.y); a[2] = f2bf(v0.z); a[3] = f2bf(v0.w);
            a[4] = f2bf(v1.x); a[5] = f2bf(v1.y); a[6] = f2bf(v1.z); a[7] = f2bf(v1.w);
            afrag[ks2] = a;
        }

#pragma unroll
        for (int i = 0; i < 12; ++i) {
            int nc   = wave * 12 + i;     // 0..23 : [Q 0-7 | K 8-15 | V 16-23]
            int proj = nc >> 3;
            int nt   = nc & 7;
            const unsigned short* wb = wpk + ((size_t)((proj * 8 + nt) * 4) * 64 + lane) * 8;
            f32x4 acc = {0.f, 0.f, 0.f, 0.f};
#pragma unroll
            for (int ks2 = 0; ks2 < 4; ++ks2) {
                short8 b = *(const short8*)(wb + (size_t)ks2 * 64 * 8);
                acc = __builtin_amdgcn_mfma_f32_16x16x32_bf16(afrag[ks2], b, acc, 0, 0, 0);
            }
            int col = nt * 16 + c;
            if (proj < 2) {
                __fp16* dst = proj ? ksh : qs;
#pragma unroll
                for (int r2 = 0; r2 < 4; ++r2) {
                    int row = g * 4 + r2;   // C/D: row=(l>>4)*4+reg, col=l&15
                    dst[row * LPITCH + col] = (__fp16)acc[r2];
                }
            } else {
                int vc = (col & 3) * 32 + (col >> 2);  // transpose: [d][kh]
#pragma unroll
                for (int r2 = 0; r2 < 4; ++r2) {
                    int row = g * 4 + r2;
                    vth[row * LPITCH + vc] = (__fp16)acc[r2];
                }
            }
        }
    }
    __syncthreads();

    // ---------------- Phase 2: per-token attention, token-stationary -------
    // 8 threads per token (tok = tid>>3, 0..15). Each pass handles TWO q-heads
    // so every K/V LDS read is shared. K/V reads: 8 distinct bcast addrs/wave,
    // 272B token pitch => the 8 16B slots tile all 32 banks (conflict-free).
    {
        const float cexp = 0.5f * 1.44269504088896340736f; // scale * log2(e)
        const int tok = tid >> 3;
        const int qb  = tid & 7;
        const __fp16* krow = ksh + tok * LPITCH;
        const __fp16* vrow = vth + tok * LPITCH;
        const __fp16* qrow = qs  + tok * LPITCH;
#pragma unroll 1
        for (int hlf = 0; hlf < 2; ++hlf) {
            const int qhA = qb + hlf * 8;   // 0..15
            const int qhB = qhA + 16;       // 16..31
            uint2 qrA = *(const uint2*)(qrow + qhA * 4);
            uint2 qrB = *(const uint2*)(qrow + qhB * 4);
            h2_t qA0 = u2h(qrA.x), qA1 = u2h(qrA.y);
            h2_t qB0 = u2h(qrB.x), qB1 = u2h(qrB.y);
            float sumA = 0.f, sumB = 0.f;
            unsigned pkA[16], pkB[16];      // exp(scores) packed f16 pairs
#pragma unroll
            for (int kp = 0; kp < 16; ++kp) {
                uint4 kr = *(const uint4*)(krow + kp * 8);  // kh = 2kp, 2kp+1
                float sA0 = fdot2(u2h(kr.x), qA0, fdot2(u2h(kr.y), qA1, 0.f));
                float sA1 = fdot2(u2h(kr.z), qA0, fdot2(u2h(kr.w), qA1, 0.f));
                float sB0 = fdot2(u2h(kr.x), qB0, fdot2(u2h(kr.y), qB1, 0.f));
                float sB1 = fdot2(u2h(kr.z), qB0, fdot2(u2h(kr.w), qB1, 0.f));
                float eA0 = EXP2F(sA0 * cexp), eA1 = EXP2F(sA1 * cexp);
                float eB0 = EXP2F(sB0 * cexp), eB1 = EXP2F(sB1 * cexp);
                sumA += eA0 + eA1; sumB += eB0 + eB1;
                pkA[kp] = pk16(eA0, eA1);
                pkB[kp] = pk16(eB0, eB1);
            }
            float aA[4], aB[4];
#pragma unroll
            for (int d = 0; d < 4; ++d) {
                float accA = 0.f, accB = 0.f;
#pragma unroll
                for (int vp = 0; vp < 4; ++vp) {
                    uint4 vr = *(const uint4*)(vrow + d * 32 + vp * 8); // kh pairs
                    accA = fdot2(u2h(pkA[vp * 4 + 0]), u2h(vr.x), accA);
                    accA = fdot2(u2h(pkA[vp * 4 + 1]), u2h(vr.y), accA);
                    accA = fdot2(u2h(pkA[vp * 4 + 2]), u2h(vr.z), accA);
                    accA = fdot2(u2h(pkA[vp * 4 + 3]), u2h(vr.w), accA);
                    accB = fdot2(u2h(pkB[vp * 4 + 0]), u2h(vr.x), accB);
                    accB = fdot2(u2h(pkB[vp * 4 + 1]), u2h(vr.y), accB);
                    accB = fdot2(u2h(pkB[vp * 4 + 2]), u2h(vr.z), accB);
                    accB = fdot2(u2h(pkB[vp * 4 + 3]), u2h(vr.w), accB);
                }
                aA[d] = accA; aB[d] = accB;
            }
            float rA = RCPF(sumA), rB = RCPF(sumB);
            __fp16* atr = at_ + tok * LPITCH;
            uint2 stA, stB;
            stA.x = pk16(aA[0] * rA, aA[1] * rA);
            stA.y = pk16(aA[2] * rA, aA[3] * rA);
            stB.x = pk16(aB[0] * rB, aB[1] * rB);
            stB.y = pk16(aB[2] * rB, aB[3] * rB);
            *(uint2*)(atr + qhA * 4) = stA;
            *(uint2*)(atr + qhB * 4) = stB;
        }
    }
    __syncthreads();

    // ---------------- Phase 3: output projection + bias (f16 MFMA) ---------
    {
        h8_t af[4];
#pragma unroll
        for (int ks2 = 0; ks2 < 4; ++ks2) {
            af[ks2] = *(const h8_t*)(at_ + c * LPITCH + ks2 * 32 + g * 8);
        }
#pragma unroll
        for (int i = 0; i < 4; ++i) {
            int nt = wave * 4 + i;
            const unsigned short* wb = wpk + ((size_t)((3 * 8 + nt) * 4) * 64 + lane) * 8;
            f32x4 acc = {0.f, 0.f, 0.f, 0.f};
#pragma unroll
            for (int ks2 = 0; ks2 < 4; ++ks2) {
                h8_t b = *(const h8_t*)(wb + (size_t)ks2 * 64 * 8);
                acc = __builtin_amdgcn_mfma_f32_16x16x32_f16(af[ks2], b, acc, 0, 0, 0);
            }
            int col = nt * 16 + c;
            float bias = bo[col];
            float* orow = out + (size_t)(bt0 + g * 4) * E + col;
#pragma unroll
            for (int r2 = 0; r2 < 4; ++r2) {
                orow[(size_t)r2 * E] = acc[r2] + bias;
            }
        }
    }
}

// ---------------------------------------------------------------------------
extern "C" void kernel_launch(void* const* d_in, const int* in_sizes, int n_in,
                              void* d_out, int out_size, void* d_ws, size_t ws_size,
                              hipStream_t stream) {
    const float* x  = (const float*)d_in[0];
    const float* Wq = (const float*)d_in[1];
    const float* Wk = (const float*)d_in[2];
    const float* Wv = (const float*)d_in[3];
    const float* Wo = (const float*)d_in[4];
    const float* bo = (const float*)d_in[5];
    unsigned short* wpk = (unsigned short*)d_ws;   // 4*8*4*64*8 halfwords = 128 KiB
    float* out = (float*)d_out;

    pack_w<<<32, 256, 0, stream>>>(Wq, Wk, Wv, Wo, wpk);
    mha_fused<<<TOKENS / BT, THREADS, 0, stream>>>(x, wpk, bo, out);
}

// Round 5
// 46.082 us; speedup vs baseline: 1.1010x; 1.1010x over previous
//
#include <hip/hip_runtime.h>

// MultiHeadAttention — fused per-token head-mixing attention.
// B=32, S=2048 -> 65536 tokens; E=128; HEADS=32; HEAD_DIM=4.
// out[t] = softmax_over_kh( Q(t)K(t)^T * 0.5 ) V(t)  @ Wo^T + bo, with
// Q/K/V = x[t] @ W{q,k,v}^T reshaped (32 heads x 4 dims).
//
// R5 (from 50us R3/R4): phase 2 moved to the MATRIX pipe.
//  Per token (one 32x32x16 f16 MFMA each):
//   S^T[kh][qh] = mfma(A=K rows, B=Q cols, k=d 4/16 slots)
//   O[d][qh]   += mfma(A=V' (m=d, plus ONES row at m=4 -> softmax denom free),
//                      B=P half, k=kh 16 slots) x2 halves, accumulating.
//  C layout 32x32: col=lane&31, row=(reg&3)+8*(reg>>2)+4*(lane>>5) — the QK
//  output's reg order IS the PV B-fragment j order (kappa(g,j)=(j&3)+8(j>>2)+4g),
//  with V' stored permuted p(kh) so A/B kappas match. Denominator lands at
//  lane (c,1) reg0 -> one shfl + rcp; O at lane (c,0) regs0-3 -> one b64 store.
//  ~60 wave-insts/token vs ~260 in the scalar-dot version (R3/R4 were
//  issue/latency-bound on that: VALUBusy 45%, 66 dependent LDS reads/thread).
//  at_ conversion RNE (R4's RTZ doubled absmax). Phases 1/3 as R4 (passing).

#define TOKENS (32 * 2048)
#define E 128
#define NH 32
#define BT 16           // tokens per block
#define THREADS 128     // 2 waves
#define LPITCH 136      // f16 elems per LDS token row (272 B)

typedef __attribute__((ext_vector_type(8))) short short8;
typedef __attribute__((ext_vector_type(4))) float f32x4;
typedef __attribute__((ext_vector_type(16))) float f32x16;
typedef __fp16 h2_t __attribute__((ext_vector_type(2)));
typedef __fp16 h8_t __attribute__((ext_vector_type(8)));

#if __has_builtin(__builtin_amdgcn_exp2f)
#define EXP2F __builtin_amdgcn_exp2f
#else
#define EXP2F exp2f
#endif

#if __has_builtin(__builtin_amdgcn_rcpf)
#define RCPF __builtin_amdgcn_rcpf
#else
#define RCPF(x) (1.0f / (x))
#endif

static __device__ __forceinline__ unsigned short f2bf(float f) {
    // round-to-nearest-even float -> bf16 bits
    unsigned u = __float_as_uint(f);
    unsigned r = (u + 0x7fffu + ((u >> 16) & 1u)) >> 16;
    return (unsigned short)r;
}

static __device__ __forceinline__ unsigned pk16(float a, float b) {
    return __builtin_bit_cast(unsigned, __builtin_amdgcn_cvt_pkrtz(a, b));
}

static __device__ __forceinline__ f32x16 zero16() {
    f32x16 z;
#pragma unroll
    for (int i = 0; i < 16; ++i) z[i] = 0.f;
    return z;
}

// V' LDS permutation: p(kh) groups the 8 kh needed by PV A-fragment lane
// (c,g) half h into one contiguous 16B run at halfword offset d*32+16h+8g.
static __device__ __forceinline__ int vperm(int kh) {
    return ((kh >> 4) & 1) * 16 + ((kh >> 2) & 1) * 8 + ((kh >> 3) & 1) * 4 + (kh & 3);
}

// ---------------------------------------------------------------------------
// Prelude: pack Wq,Wk,Wv (bf16) and Wo (f16) from fp32 [out=128][in=128] into
// MFMA B-fragment order: wpk[proj][nt(8)][ks(4)][lane(64)][j(8)]; for lane l
// (c=l&15, g=l>>4): elem j = W[nt*16+c][ks*32 + g*8 + j].
// ---------------------------------------------------------------------------
__global__ void pack_w(const float* __restrict__ Wq, const float* __restrict__ Wk,
                       const float* __restrict__ Wv, const float* __restrict__ Wo,
                       unsigned short* __restrict__ wpk) {
    int idx = blockIdx.x * blockDim.x + threadIdx.x;   // 4*8*4*64 = 8192
    if (idx >= 4 * 8 * 4 * 64) return;
    int lane = idx & 63;
    int ks   = (idx >> 6) & 3;
    int nt   = (idx >> 8) & 7;
    int proj = idx >> 11;
    const float* W = (proj == 0) ? Wq : (proj == 1) ? Wk : (proj == 2) ? Wv : Wo;
    int c = lane & 15, g = lane >> 4;
    const float* src = W + (size_t)(nt * 16 + c) * E + ks * 32 + g * 8;
    unsigned short* dst = wpk + (size_t)idx * 8;
    if (proj < 3) {
#pragma unroll
        for (int j = 0; j < 8; ++j) dst[j] = f2bf(src[j]);
    } else {
#pragma unroll
        for (int j = 0; j < 8; ++j)
            dst[j] = __builtin_bit_cast(unsigned short, (__fp16)src[j]);
    }
}

// ---------------------------------------------------------------------------
// Main fused kernel: 16 tokens per block, 2 waves.
// ---------------------------------------------------------------------------
__global__ __launch_bounds__(THREADS) void mha_fused(
        const float* __restrict__ x, const unsigned short* __restrict__ wpk,
        const float* __restrict__ bo, float* __restrict__ out) {
    __shared__ __fp16 qs [BT * LPITCH];          // Q rows  [tok][qh*4+d]   f16
    __shared__ __fp16 ksh[BT * LPITCH];          // K rows  [tok][kh*4+d]   f16
    __shared__ __fp16 vth[BT * LPITCH];          // V''     [tok][d*32+p(kh)] f16
    __shared__ __fp16 at_[BT * LPITCH];          // attended [tok][qh*4+d]  f16

    const int tid  = threadIdx.x;
    const int wave = tid >> 6;
    const int lane = tid & 63;
    const int c = lane & 15, g = lane >> 4;
    const int bt0 = blockIdx.x * BT;

    // ---------------- Phase 1: Q,K,V projections (fused N=384) -------------
    {
        // A fragments: X rows in bf16, kappa(g,j)=g*8+j, reused over all nc
        short8 afrag[4];
        const float* xrow = x + (size_t)(bt0 + c) * E;
#pragma unroll
        for (int ks2 = 0; ks2 < 4; ++ks2) {
            const float* p = xrow + ks2 * 32 + g * 8;
            float4 v0 = *(const float4*)(p);
            float4 v1 = *(const float4*)(p + 4);
            short8 a;
            a[0] = f2bf(v0.x); a[1] = f2bf(v0.y); a[2] = f2bf(v0.z); a[3] = f2bf(v0.w);
            a[4] = f2bf(v1.x); a[5] = f2bf(v1.y); a[6] = f2bf(v1.z); a[7] = f2bf(v1.w);
            afrag[ks2] = a;
        }

#pragma unroll
        for (int i = 0; i < 12; ++i) {
            int nc   = wave * 12 + i;     // 0..23 : [Q 0-7 | K 8-15 | V 16-23]
            int proj = nc >> 3;
            int nt   = nc & 7;
            const unsigned short* wb = wpk + ((size_t)((proj * 8 + nt) * 4) * 64 + lane) * 8;
            f32x4 acc = {0.f, 0.f, 0.f, 0.f};
#pragma unroll
            for (int ks2 = 0; ks2 < 4; ++ks2) {
                short8 b = *(const short8*)(wb + (size_t)ks2 * 64 * 8);
                acc = __builtin_amdgcn_mfma_f32_16x16x32_bf16(afrag[ks2], b, acc, 0, 0, 0);
            }
            int col = nt * 16 + c;
            if (proj < 2) {
                __fp16* dst = proj ? ksh : qs;
#pragma unroll
                for (int r2 = 0; r2 < 4; ++r2) {
                    int row = g * 4 + r2;   // C/D: row=(l>>4)*4+reg, col=l&15
                    dst[row * LPITCH + col] = (__fp16)acc[r2];
                }
            } else {
                int vc = (col & 3) * 32 + vperm(col >> 2);  // V'' perm layout
#pragma unroll
                for (int r2 = 0; r2 < 4; ++r2) {
                    int row = g * 4 + r2;
                    vth[row * LPITCH + vc] = (__fp16)acc[r2];
                }
            }
        }
    }
    __syncthreads();

    // ---------------- Phase 2: per-token attention on the MFMA pipe --------
    // One token per wave-step; 8 tokens per wave.
    {
        const float cexp = 0.5f * 1.44269504088896340736f; // scale * log2(e)
        const int c32 = lane & 31;      // C col / A-B outer index
        const int gg  = lane >> 5;      // k-slot group
        const uint4 ONES4 = make_uint4(0x3C003C00u, 0x3C003C00u, 0x3C003C00u, 0x3C003C00u);
#pragma unroll 2
        for (int t8 = 0; t8 < 8; ++t8) {
            const int tok = wave * 8 + t8;
            const __fp16* qrow = qs  + tok * LPITCH;
            const __fp16* krow = ksh + tok * LPITCH;
            const __fp16* vrow = vth + tok * LPITCH;

            // A=K fragment: m=kh=c32, k=d at g=0 j0-3; all other slots ZERO
            // B=Q fragment: n=qh=c32, same kappa. (zero both: garbage*0=NaN risk)
            uint4 kraw = {0u, 0u, 0u, 0u}, qraw = {0u, 0u, 0u, 0u};
            if (gg == 0) {
                uint2 kk = *(const uint2*)(krow + c32 * 4);
                uint2 qq = *(const uint2*)(qrow + c32 * 4);
                kraw.x = kk.x; kraw.y = kk.y;
                qraw.x = qq.x; qraw.y = qq.y;
            }
            h8_t kf = __builtin_bit_cast(h8_t, kraw);
            h8_t qf = __builtin_bit_cast(h8_t, qraw);

            // S^T[kh][qh]: lane (c,g) reg r = S[kh=(r&3)+8(r>>2)+4g][qh=c]
            f32x16 sc = zero16();
            sc = __builtin_amdgcn_mfma_f32_32x32x16_f16(kf, qf, sc, 0, 0, 0);

            // exp2; reg order == PV B-fragment j order (kappa matched)
            float e[16];
#pragma unroll
            for (int r = 0; r < 16; ++r) e[r] = EXP2F(sc[r] * cexp);
            uint4 p0u = make_uint4(pk16(e[0], e[1]),  pk16(e[2], e[3]),
                                   pk16(e[4], e[5]),  pk16(e[6], e[7]));
            uint4 p1u = make_uint4(pk16(e[8], e[9]),  pk16(e[10], e[11]),
                                   pk16(e[12], e[13]), pk16(e[14], e[15]));
            h8_t p0 = __builtin_bit_cast(h8_t, p0u);
            h8_t p1 = __builtin_bit_cast(h8_t, p1u);

            // A=V' fragment: m=c32 (d rows 0-3, ONES row 4 -> denominator,
            // rows 5+ replicated V rows -> discarded). k=kh via p(kh) layout.
            uint4 vr0 = *(const uint4*)(vrow + (c32 & 3) * 32 + gg * 8);
            uint4 vr1 = *(const uint4*)(vrow + (c32 & 3) * 32 + 16 + gg * 8);
            if (c32 == 4) { vr0 = ONES4; vr1 = ONES4; }
            h8_t v0f = __builtin_bit_cast(h8_t, vr0);
            h8_t v1f = __builtin_bit_cast(h8_t, vr1);

            f32x16 pv = zero16();
            pv = __builtin_amdgcn_mfma_f32_32x32x16_f16(v0f, p0, pv, 0, 0, 0);
            pv = __builtin_amdgcn_mfma_f32_32x32x16_f16(v1f, p1, pv, 0, 0, 0);

            // denominator: row 4 -> lane (c,1) reg0. O[d]: lane (c,0) regs0-3.
            float sum  = __shfl(pv[0], c32 + 32, 64);
            float rinv = RCPF(sum);
            if (lane < 32) {
                unsigned short h0 = __builtin_bit_cast(unsigned short, (__fp16)(pv[0] * rinv));
                unsigned short h1 = __builtin_bit_cast(unsigned short, (__fp16)(pv[1] * rinv));
                unsigned short h2 = __builtin_bit_cast(unsigned short, (__fp16)(pv[2] * rinv));
                unsigned short h3 = __builtin_bit_cast(unsigned short, (__fp16)(pv[3] * rinv));
                uint2 st;
                st.x = (unsigned)h0 | ((unsigned)h1 << 16);
                st.y = (unsigned)h2 | ((unsigned)h3 << 16);
                *(uint2*)(at_ + tok * LPITCH + c32 * 4) = st;
            }
        }
    }
    __syncthreads();

    // ---------------- Phase 3: output projection + bias (f16 MFMA) ---------
    {
        h8_t af[4];
#pragma unroll
        for (int ks2 = 0; ks2 < 4; ++ks2) {
            af[ks2] = *(const h8_t*)(at_ + c * LPITCH + ks2 * 32 + g * 8);
        }
#pragma unroll
        for (int i = 0; i < 4; ++i) {
            int nt = wave * 4 + i;
            const unsigned short* wb = wpk + ((size_t)((3 * 8 + nt) * 4) * 64 + lane) * 8;
            f32x4 acc = {0.f, 0.f, 0.f, 0.f};
#pragma unroll
            for (int ks2 = 0; ks2 < 4; ++ks2) {
                h8_t b = *(const h8_t*)(wb + (size_t)ks2 * 64 * 8);
                acc = __builtin_amdgcn_mfma_f32_16x16x32_f16(af[ks2], b, acc, 0, 0, 0);
            }
            int col = nt * 16 + c;
            float bias = bo[col];
            float* orow = out + (size_t)(bt0 + g * 4) * E + col;
#pragma unroll
            for (int r2 = 0; r2 < 4; ++r2) {
                orow[(size_t)r2 * E] = acc[r2] + bias;
            }
        }
    }
}

// ---------------------------------------------------------------------------
extern "C" void kernel_launch(void* const* d_in, const int* in_sizes, int n_in,
                              void* d_out, int out_size, void* d_ws, size_t ws_size,
                              hipStream_t stream) {
    const float* x  = (const float*)d_in[0];
    const float* Wq = (const float*)d_in[1];
    const float* Wk = (const float*)d_in[2];
    const float* Wv = (const float*)d_in[3];
    const float* Wo = (const float*)d_in[4];
    const float* bo = (const float*)d_in[5];
    unsigned short* wpk = (unsigned short*)d_ws;   // 4*8*4*64*8 halfwords = 128 KiB
    float* out = (float*)d_out;

    pack_w<<<32, 256, 0, stream>>>(Wq, Wk, Wv, Wo, wpk);
    mha_fused<<<TOKENS / BT, THREADS, 0, stream>>>(x, wpk, bo, out);
}